// Round 10
// baseline (258.304 us; speedup 1.0000x reference)
//
#include <hip/hip_runtime.h>

#define N_NODES 50000
#define N_EDGES 800000
#define NUM_GRAPHS 16
#define NUM_CLASSES 247
#define SCAN_BLOCKS ((N_NODES + 255) / 256)  // 196
#define CSR_CAP (N_EDGES + 7 * N_NODES)      // degrees padded to multiples of 8

typedef __attribute__((ext_vector_type(8))) short bf16x8;
typedef __attribute__((ext_vector_type(4))) float f32x4;
typedef __attribute__((ext_vector_type(2))) float f32x2;

#if __has_builtin(__builtin_amdgcn_cvt_pk_f32_fp8) && __has_builtin(__builtin_amdgcn_cvt_pk_fp8_f32)
#define HW_FP8 1
#else
#define HW_FP8 0
#endif

static inline int nblk(long n) { return (int)((n + 255) / 256); }

__device__ __forceinline__ float bfl(unsigned short u) {
    return __uint_as_float((unsigned)u << 16);
}
__device__ __forceinline__ unsigned short bf16_rne(float f) {
    unsigned u = __float_as_uint(f);
    u += 0x7FFF + ((u >> 16) & 1);
    return (unsigned short)(u >> 16);
}

// ---- 8-bit activation codec -------------------------------------------------
// Preferred: HW fp8 e4m3 (v_cvt_pk_*). Fallback: software unsigned-e4m4.
// Values carry a x64 scale shift (encoded in producers); Wt2/Wt3 pre-divided.
__device__ __forceinline__ unsigned q8(float v) {  // sw e4m4 (fallback)
    if (v < 0.015625f) return 0u;
    unsigned u = __float_as_uint(v) - (120u << 23);
    u += 0x3FFFF + ((u >> 19) & 1);
    unsigned q = u >> 19;
    return q > 255u ? 255u : q;
}
__device__ __forceinline__ float dq8(unsigned x) {  // sw e4m4 (fallback)
    float f = __uint_as_float((x + 1920u) << 19);
    return x ? f : 0.0f;
}

__device__ __forceinline__ void dq2(unsigned v, float& lo, float& hi) {
#if HW_FP8
    f32x2 t = __builtin_amdgcn_cvt_pk_f32_fp8((int)v, false);
    lo = t[0];
    hi = t[1];
#else
    lo = dq8(v & 0xff);
    hi = dq8(v >> 8);
#endif
}
__device__ __forceinline__ float dq1(unsigned v) {
#if HW_FP8
    f32x2 t = __builtin_amdgcn_cvt_pk_f32_fp8((int)(v & 0xff), false);
    return t[0];
#else
    return dq8(v & 0xff);
#endif
}
__device__ __forceinline__ unsigned enc1(float v) {
#if HW_FP8
    return (unsigned)__builtin_amdgcn_cvt_pk_fp8_f32(v, 0.0f, 0, false) & 0xffu;
#else
    return q8(v);
#endif
}
__device__ __forceinline__ unsigned enc4(float a, float b, float c, float d) {
#if HW_FP8
    int r = __builtin_amdgcn_cvt_pk_fp8_f32(a, b, 0, false);
    r = __builtin_amdgcn_cvt_pk_fp8_f32(c, d, r, true);
    return (unsigned)r;
#else
    return q8(a) | (q8(b) << 8) | (q8(c) << 16) | (q8(d) << 24);
#endif
}

// ---- degree histogram into 8 XCD-local copies (pure histogram now) ---------
// Block 0 additionally zeroes psum/pcnt + X/Y sentinel rows.
__global__ void k_deg(const int* __restrict__ col, int* __restrict__ degc,
                      float* __restrict__ psum,
                      unsigned char* __restrict__ X, unsigned char* __restrict__ Y,
                      int E) {
    if (blockIdx.x == 0) {
        for (int i = threadIdx.x; i < NUM_GRAPHS * 256 + NUM_GRAPHS; i += 256)
            psum[i] = 0.0f;
        if (threadIdx.x < 64) X[(size_t)N_NODES * 64 + threadIdx.x] = 0;
        if (threadIdx.x < 128) Y[(size_t)N_NODES * 128 + threadIdx.x] = 0;
    }
    int e = blockIdx.x * blockDim.x + threadIdx.x;
    if (e >= E) return;
    int c8 = (e >> 8) & 7;
    atomicAdd(&degc[c8 * N_NODES + col[e]], 1);
}

// ---- scan phase 1: per-block exclusive scan of PADDED degree + batch hist --
__global__ __launch_bounds__(256) void k_scan1(const int* __restrict__ degc,
                                               int* __restrict__ rowptr,
                                               int* __restrict__ bsum,
                                               const int* __restrict__ batch,
                                               float* __restrict__ pcnt, int N) {
    __shared__ int buf[256];
    __shared__ int hist[NUM_GRAPHS];
    int t = threadIdx.x;
    if (t < NUM_GRAPHS) hist[t] = 0;
    __syncthreads();  // hist must be zeroed before any wave's atomicAdd
    int i = blockIdx.x * 256 + t;
    int v = 0;
    if (i < N) {
        int tot = 0;
#pragma unroll
        for (int c = 0; c < 8; ++c) tot += degc[c * N_NODES + i];
        v = (tot + 7) & ~7;  // padded degree
        atomicAdd(&hist[batch[i]], 1);
    }
    buf[t] = v;
    __syncthreads();
#pragma unroll
    for (int off = 1; off < 256; off <<= 1) {
        int tmp = (t >= off) ? buf[t - off] : 0;
        __syncthreads();
        if (t >= off) buf[t] += tmp;
        __syncthreads();
    }
    if (i < N) rowptr[i] = buf[t] - v;  // exclusive within block
    if (t == 255) bsum[blockIdx.x] = buf[255];
    if (t < NUM_GRAPHS && hist[t] > 0) atomicAdd(&pcnt[t], (float)hist[t]);
}

// ---- scan phase 2 (folded): block-offset + per-copy slot counters + dinv +
//      xs (float4 rows) + Wt casts + sentinel-fill + rowptr[N] ---------------
__global__ __launch_bounds__(256) void k_scan3(int* __restrict__ rowptr,
                                               const int* __restrict__ bsum,
                                               const int* __restrict__ degc,
                                               int* __restrict__ basecnt,
                                               float* __restrict__ dinv,
                                               const float* __restrict__ x,
                                               float* __restrict__ xs,
                                               unsigned short* __restrict__ csr,
                                               const float* __restrict__ W2,
                                               const float* __restrict__ W3,
                                               unsigned short* __restrict__ Wt2,
                                               unsigned short* __restrict__ Wt3,
                                               int N) {
    __shared__ int red[256];
    int t = threadIdx.x;
    int b = blockIdx.x;
    red[t] = (t < b) ? bsum[t] : 0;  // b <= 195 < 256
    __syncthreads();
#pragma unroll
    for (int off = 128; off > 0; off >>= 1) {
        if (t < off) red[t] += red[t + off];
        __syncthreads();
    }
    int boff = red[0];
    int i = b * 256 + t;
    if (i < N) {
        int rp = rowptr[i] + boff;
        rowptr[i] = rp;
        int run = rp, tot = 0;
#pragma unroll
        for (int c = 0; c < 8; ++c) {
            int d = degc[c * N_NODES + i];
            basecnt[c * N_NODES + i] = run;  // k_fill's atomic slot counters
            run += d;
            tot += d;
        }
        int pdeg = (tot + 7) & ~7;
        // sentinel-fill pad slots -> point at the all-zero row N_NODES
        for (int j = rp + tot; j < rp + pdeg; ++j) csr[j] = (unsigned short)N_NODES;
        if (i == N - 1) rowptr[N] = rp + pdeg;  // padded total
        float dv = rsqrtf((float)tot + 1.0f);   // +1 = self loop
        dinv[i] = dv;
        f32x4 xv = {dv * x[i * 3 + 0], dv * x[i * 3 + 1], dv * x[i * 3 + 2], 0.0f};
        *(f32x4*)(xs + 4 * i) = xv;
    }
    if (i == 0) {  // zero sentinel row of xs
        f32x4 z = {0.0f, 0.0f, 0.0f, 0.0f};
        *(f32x4*)(xs + 4 * N) = z;
    }
    // folded weight cast+transpose (with /64 scale compensation)
    if (i < 64 * 128) {                       // Wt2: [f=128][k=64]
        int f = i / 64, k = i % 64;
        Wt2[i] = bf16_rne(W2[k * 128 + f] * 0.015625f);
    } else if (i < 64 * 128 + 128 * 256) {    // Wt3: [f=256][k=128]
        int j = i - 64 * 128;
        int f = j / 128, k = j % 128;
        Wt3[j] = bf16_rne(W3[k * 256 + f] * 0.015625f);
    }
}

// ---- CSR fill: rank re-derived via atomic on basecnt (pos array removed) ---
__global__ void k_fill(const int* __restrict__ row, const int* __restrict__ col,
                       int* __restrict__ basecnt, unsigned short* __restrict__ csr,
                       int E) {
    int e = blockIdx.x * blockDim.x + threadIdx.x;
    if (e >= E) return;
    int c8 = (e >> 8) & 7;
    int slot = atomicAdd(&basecnt[c8 * N_NODES + col[e]], 1);
    csr[slot] = (unsigned short)row[e];
}

// ---- fused layer 1: p1 = dv*(xs[v]+Σxs[r]); X = enc(64*dv*relu(p1 W1+b1)) --
// xs rows are float4 (one aligned dwordx4 request per edge).
__global__ void k_layer1(const float* __restrict__ xs, const float* __restrict__ dinv,
                         const int* __restrict__ rowptr,
                         const unsigned short* __restrict__ csr_src,
                         const float* __restrict__ W1, const float* __restrict__ b1,
                         unsigned char* __restrict__ out, int N) {
    int v = blockIdx.x * blockDim.x + threadIdx.x;
    if (v >= N) return;
    const unsigned* csr32 = (const unsigned*)csr_src;
    f32x4 a = *(const f32x4*)(xs + 4 * v);
    int j = rowptr[v];
    int j1 = rowptr[v + 1];
    for (; j + 4 <= j1; j += 4) {  // j stays multiple of 4 (rowptr mult of 8)
        unsigned p0 = csr32[(j >> 1) + 0];
        unsigned p1 = csr32[(j >> 1) + 1];
        int r0 = p0 & 0xFFFFu, r1 = p0 >> 16;
        int r2 = p1 & 0xFFFFu, r3 = p1 >> 16;
        f32x4 x0 = *(const f32x4*)(xs + 4 * r0);
        f32x4 x1 = *(const f32x4*)(xs + 4 * r1);
        f32x4 x2 = *(const f32x4*)(xs + 4 * r2);
        f32x4 x3 = *(const f32x4*)(xs + 4 * r3);
        a[0] += x0[0]; a[1] += x0[1]; a[2] += x0[2];
        a[0] += x1[0]; a[1] += x1[1]; a[2] += x1[2];
        a[0] += x2[0]; a[1] += x2[1]; a[2] += x2[2];
        a[0] += x3[0]; a[1] += x3[1]; a[2] += x3[2];
    }
    for (; j < j1; ++j) {  // dead with padded degrees
        int r = csr_src[j];
        f32x4 xv = *(const f32x4*)(xs + 4 * r);
        a[0] += xv[0]; a[1] += xv[1]; a[2] += xv[2];
    }
    float dv = dinv[v];
    float p0 = dv * a[0], p1 = dv * a[1], p2 = dv * a[2];
    float dv64 = dv * 64.0f;  // pre-scale for next prop + x64 codec shift
    unsigned char* ov = out + (long)v * 64;
#pragma unroll
    for (int f = 0; f < 64; f += 4) {
        float s[4];
#pragma unroll
        for (int t = 0; t < 4; ++t) {
            float sv = fmaf(p0, W1[f + t],
                       fmaf(p1, W1[64 + f + t],
                       fmaf(p2, W1[128 + f + t], b1[f + t])));
            s[t] = fmaxf(sv, 0.0f) * dv64;
        }
        *(unsigned*)(ov + f) = enc4(s[0], s[1], s[2], s[3]);
    }
}

// ---- FUSED prop + MFMA GEMM per 16-row m-tile; optional fused mean-pool ----
// R7 structure (4-row simultaneous gather); R9 change: csr is ushort, index
// pairs loaded as uints (j stays a multiple of 8 -> uint-aligned).
template <int K, int F, bool PRESCALE, bool POOL>
__global__ __launch_bounds__(256, 4) void k_fused(
        const unsigned char* __restrict__ h, const float* __restrict__ dinv,
        const int* __restrict__ rowptr, const unsigned short* __restrict__ csr_src,
        const unsigned short* __restrict__ Wt, const float* __restrict__ b,
        unsigned char* __restrict__ out, const int* __restrict__ batch,
        float* __restrict__ psum, int N) {
    constexpr int NF = F / 16;    // f-tiles: 8 (F=128) / 16 (F=256)
    constexpr int FPW = NF / 4;   // f-tiles per wave: 2 / 4
    constexpr int KB = K / 32;    // k-blocks: 2 / 4
    constexpr int KL = K / 64;    // features (bytes) per lane in prop: 1 / 2
    constexpr int PADK = K + 8;
    __shared__ unsigned short plds[16][PADK];
    const unsigned* csr32 = (const unsigned*)csr_src;
    int wave = threadIdx.x >> 6;
    int lane = threadIdx.x & 63;
    int m0 = blockIdx.x * 16;

    // ---- phase 1: 4 rows per wave, simultaneous 8-wide gather batches ----
    int vr = m0 + wave * 4;
    float acc[4][KL];
    int j[4], j1[4];
#pragma unroll
    for (int r = 0; r < 4; ++r) {
        const unsigned char* hv = h + (long)(vr + r) * K + lane * KL;
        if (KL == 2) {
            unsigned u = *(const unsigned short*)hv;
            dq2(u, acc[r][0], acc[r][1]);
        } else {
            acc[r][0] = dq1(hv[0]);
        }
        j[r]  = __builtin_amdgcn_readfirstlane(rowptr[vr + r]);
        j1[r] = __builtin_amdgcn_readfirstlane(rowptr[vr + r + 1]);
    }
    while ((j[0] < j1[0]) || (j[1] < j1[1]) || (j[2] < j1[2]) || (j[3] < j1[3])) {
        bool act[4];
        int idx[4][8];
        unsigned tv[4][8];
        // phase a: index loads (uniform address, packed ushort pairs)
#pragma unroll
        for (int r = 0; r < 4; ++r) {
            act[r] = j[r] < j1[r];
            if (act[r]) {
#pragma unroll
                for (int u = 0; u < 4; ++u) {
                    unsigned pk = csr32[(j[r] >> 1) + u];
                    idx[r][2 * u]     = pk & 0xFFFFu;
                    idx[r][2 * u + 1] = pk >> 16;
                }
            }
        }
        // phase b: issue all gathers (up to 32 in flight)
#pragma unroll
        for (int r = 0; r < 4; ++r) {
            if (act[r]) {
                if (KL == 2) {
#pragma unroll
                    for (int u = 0; u < 8; ++u)
                        tv[r][u] = *(const unsigned short*)(h + (long)idx[r][u] * K + lane * 2);
                } else {
#pragma unroll
                    for (int u = 0; u < 8; ++u)
                        tv[r][u] = h[(long)idx[r][u] * K + lane];
                }
            }
        }
        // phase c: accumulate
#pragma unroll
        for (int r = 0; r < 4; ++r) {
            if (act[r]) {
                if (KL == 2) {
#pragma unroll
                    for (int u = 0; u < 8; ++u) {
                        float lo, hi;
                        dq2(tv[r][u], lo, hi);
                        acc[r][0] += lo;
                        acc[r][1] += hi;
                    }
                } else {
#pragma unroll
                    for (int u = 0; u < 8; ++u) acc[r][0] += dq1(tv[r][u]);
                }
                j[r] += 8;
            }
        }
    }
#pragma unroll
    for (int r = 0; r < 4; ++r) {
        float dv = dinv[vr + r];
        int rla = wave * 4 + r;
        if (KL == 2) {
            unsigned p = (unsigned)bf16_rne(dv * acc[r][0]) |
                         ((unsigned)bf16_rne(dv * acc[r][1]) << 16);
            *(unsigned*)&plds[rla][lane * 2] = p;
        } else {
            plds[rla][lane] = bf16_rne(dv * acc[r][0]);
        }
    }
    __syncthreads();

    // ---- phase 2: MFMA (layout verified R9/R11) ----
    int quad = lane >> 4;
    int l16 = lane & 15;
    bf16x8 afr[KB];
#pragma unroll
    for (int kb = 0; kb < KB; ++kb)
        afr[kb] = *(const bf16x8*)(const void*)&plds[l16][kb * 32 + quad * 8];
#pragma unroll
    for (int fi = 0; fi < FPW; ++fi) {
        int f0 = (wave * FPW + fi) * 16;
        const unsigned short* wrow = Wt + (long)(f0 + l16) * K + quad * 8;
        f32x4 acc4 = {0.f, 0.f, 0.f, 0.f};
#pragma unroll
        for (int kb = 0; kb < KB; ++kb) {
            bf16x8 bb = *(const bf16x8*)(const void*)(wrow + kb * 32);
            acc4 = __builtin_amdgcn_mfma_f32_16x16x32_bf16(afr[kb], bb, acc4, 0, 0, 0);
        }
        float bias = b[f0 + l16];
        if (POOL) {
            int g0 = batch[m0];
            int g15 = batch[m0 + 15];
            if (g0 == g15) {  // uniform block (all but ~15 of 3125)
                float s = fmaxf(acc4[0] + bias, 0.0f);
                s += fmaxf(acc4[1] + bias, 0.0f);
                s += fmaxf(acc4[2] + bias, 0.0f);
                s += fmaxf(acc4[3] + bias, 0.0f);
                s += __shfl_xor(s, 16);
                s += __shfl_xor(s, 32);
                if (quad == 0) atomicAdd(&psum[g0 * 256 + f0 + l16], s);
            } else {  // graph boundary inside block: per-element atomics
#pragma unroll
                for (int r = 0; r < 4; ++r) {
                    int m = m0 + quad * 4 + r;
                    float val = fmaxf(acc4[r] + bias, 0.0f);
                    atomicAdd(&psum[batch[m] * 256 + f0 + l16], val);
                }
            }
        } else {
#pragma unroll
            for (int r = 0; r < 4; ++r) {
                int m = m0 + quad * 4 + r;
                float val = fmaxf(acc4[r] + bias, 0.0f);
                if (PRESCALE) val *= dinv[m] * 64.0f;  // prop pre-scale + codec shift
                out[(long)m * F + f0 + l16] = (unsigned char)enc1(val);
            }
        }
    }
}

// ---- final FC --------------------------------------------------------------
__global__ void k_fc(const float* __restrict__ psum, const float* __restrict__ pcnt,
                     const float* __restrict__ Wfc, const float* __restrict__ bfc,
                     float* __restrict__ out) {
    int tid = blockIdx.x * blockDim.x + threadIdx.x;
    if (tid >= NUM_GRAPHS * NUM_CLASSES) return;
    int g = tid / NUM_CLASSES;
    int c = tid % NUM_CLASSES;
    float s = 0.0f;
#pragma unroll 8
    for (int k = 0; k < 256; ++k) s = fmaf(psum[g * 256 + k], Wfc[k * NUM_CLASSES + c], s);
    float cnt = pcnt[g];
    cnt = cnt > 1.0f ? cnt : 1.0f;
    out[tid] = s / cnt + bfc[c];
}

extern "C" void kernel_launch(void* const* d_in, const int* in_sizes, int n_in,
                              void* d_out, int out_size, void* d_ws, size_t ws_size,
                              hipStream_t stream) {
    const float* x     = (const float*)d_in[0];
    const int*   ei    = (const int*)d_in[1];
    const int*   batch = (const int*)d_in[2];
    const float* W1    = (const float*)d_in[3];
    const float* b1    = (const float*)d_in[4];
    const float* W2    = (const float*)d_in[5];
    const float* b2    = (const float*)d_in[6];
    const float* W3    = (const float*)d_in[7];
    const float* b3    = (const float*)d_in[8];
    const float* Wfc   = (const float*)d_in[9];
    const float* bfc   = (const float*)d_in[10];
    float* out = (float*)d_out;

    const int* row = ei;            // src
    const int* col = ei + N_EDGES;  // dst

    // ---- workspace layout (R9): xs is float4 rows; csr is ushort; pos gone.
    // X/Y stay 128-B aligned (R8 invariant). Byte offsets:
    //   xs     @ 0         ((N+1)*16 B = 800016 -> pad 800128)
    //   dinv   @ 800128    (200000 B)
    //   psum   @ 1000128   (16384 B)
    //   pcnt   @ 1016512   (64 B)
    //   X      @ 1016576   (128-aligned: /128 = 7942; (N+1)*64 = 3200064 -> pad 3200128)
    //   Y      @ 4216704   (128-aligned: /128 = 32943; (N+1)*128 = 6400128)
    //   Wt2    @ 10616832  (16384 B)
    //   Wt3    @ 10633216  (65536 B)
    //   degc   @ 10698752  (1600000 B)
    //   basecnt@ 12298752  (1600000 B)
    //   rowptr @ 13898752  (200004 -> pad 200064)
    //   csr16  @ 14098816  (CSR_CAP*2 = 2300000 B)
    //   bsum   @ 16398816  (784 B)
    unsigned char* ws = (unsigned char*)d_ws;
    float*  xs   = (float*)ws;
    float*  dinv = (float*)(ws + 800128);
    float*  psum = (float*)(ws + 1000128);
    float*  pcnt = (float*)(ws + 1016512);
    unsigned char* X = ws + 1016576;
    unsigned char* Y = ws + 4216704;
    unsigned short* Wt2 = (unsigned short*)(ws + 10616832);
    unsigned short* Wt3 = (unsigned short*)(ws + 10633216);
    int* degc    = (int*)(ws + 10698752);
    int* basecnt = (int*)(ws + 12298752);
    int* rowptr  = (int*)(ws + 13898752);
    unsigned short* csr16 = (unsigned short*)(ws + 14098816);
    int* bsum    = (int*)(ws + 16398816);

    // single memset: degc must be zero before k_deg's atomics
    hipMemsetAsync(degc, 0, 8 * N_NODES * sizeof(int), stream);

    // ---- CSR build + norms + pre-scaled x + weight casts ----
    // (k_deg block 0 also zeroes psum/pcnt and the X/Y sentinel rows)
    k_deg<<<nblk(N_EDGES), 256, 0, stream>>>(col, degc, psum, X, Y, N_EDGES);
    k_scan1<<<SCAN_BLOCKS, 256, 0, stream>>>(degc, rowptr, bsum, batch, pcnt, N_NODES);
    k_scan3<<<SCAN_BLOCKS, 256, 0, stream>>>(rowptr, bsum, degc, basecnt, dinv, x, xs,
                                             csr16, W2, W3, Wt2, Wt3, N_NODES);
    k_fill<<<nblk(N_EDGES), 256, 0, stream>>>(row, col, basecnt, csr16, N_EDGES);

    // ---- layer 1 (fused prop+linear): X = enc(64*d*relu((A~x)W1+b1)) -------
    k_layer1<<<nblk(N_NODES), 256, 0, stream>>>(xs, dinv, rowptr, csr16, W1, b1, X, N_NODES);

    int mtiles = N_NODES / 16;  // 3125, exact

    // ---- layer 2 fused: Y = enc(64*d*relu((A~-apply X) W2 + b2)) -----------
    k_fused<64, 128, true, false><<<mtiles, 256, 0, stream>>>(
        X, dinv, rowptr, csr16, Wt2, b2, Y, batch, psum, N_NODES);

    // ---- layer 3 fused + POOL: psum += relu((A~-apply Y) W3 + b3) ----------
    k_fused<128, 256, false, true><<<mtiles, 256, 0, stream>>>(
        Y, dinv, rowptr, csr16, Wt3, b3, (unsigned char*)nullptr, batch, psum, N_NODES);

    // ---- FC ----
    k_fc<<<nblk(NUM_GRAPHS * NUM_CLASSES), 256, 0, stream>>>(psum, pcnt, Wfc, bfc, out);
}

// Round 11
// 227.084 us; speedup vs baseline: 1.1375x; 1.1375x over previous
//
#include <hip/hip_runtime.h>

#define N_NODES 50000
#define N_EDGES 800000
#define NUM_GRAPHS 16
#define NUM_CLASSES 247
#define SCAN_BLOCKS ((N_NODES + 255) / 256)  // 196
#define CSR_CAP (N_EDGES + 7 * N_NODES)      // degrees padded to multiples of 8

typedef __attribute__((ext_vector_type(8))) short bf16x8;
typedef __attribute__((ext_vector_type(4))) float f32x4;
typedef __attribute__((ext_vector_type(2))) float f32x2;

#if __has_builtin(__builtin_amdgcn_cvt_pk_f32_fp8) && __has_builtin(__builtin_amdgcn_cvt_pk_fp8_f32)
#define HW_FP8 1
#else
#define HW_FP8 0
#endif

static inline int nblk(long n) { return (int)((n + 255) / 256); }

__device__ __forceinline__ float bfl(unsigned short u) {
    return __uint_as_float((unsigned)u << 16);
}
__device__ __forceinline__ unsigned short bf16_rne(float f) {
    unsigned u = __float_as_uint(f);
    u += 0x7FFF + ((u >> 16) & 1);
    return (unsigned short)(u >> 16);
}

// ---- 8-bit activation codec -------------------------------------------------
// Preferred: HW fp8 e4m3 (v_cvt_pk_*). Fallback: software unsigned-e4m4.
// Values carry a x64 scale shift (encoded in producers); Wt2/Wt3 pre-divided.
__device__ __forceinline__ unsigned q8(float v) {  // sw e4m4 (fallback)
    if (v < 0.015625f) return 0u;
    unsigned u = __float_as_uint(v) - (120u << 23);
    u += 0x3FFFF + ((u >> 19) & 1);
    unsigned q = u >> 19;
    return q > 255u ? 255u : q;
}
__device__ __forceinline__ float dq8(unsigned x) {  // sw e4m4 (fallback)
    float f = __uint_as_float((x + 1920u) << 19);
    return x ? f : 0.0f;
}

__device__ __forceinline__ void dq2(unsigned v, float& lo, float& hi) {
#if HW_FP8
    f32x2 t = __builtin_amdgcn_cvt_pk_f32_fp8((int)v, false);
    lo = t[0];
    hi = t[1];
#else
    lo = dq8(v & 0xff);
    hi = dq8(v >> 8);
#endif
}
__device__ __forceinline__ float dq1(unsigned v) {
#if HW_FP8
    f32x2 t = __builtin_amdgcn_cvt_pk_f32_fp8((int)(v & 0xff), false);
    return t[0];
#else
    return dq8(v & 0xff);
#endif
}
__device__ __forceinline__ unsigned enc1(float v) {
#if HW_FP8
    return (unsigned)__builtin_amdgcn_cvt_pk_fp8_f32(v, 0.0f, 0, false) & 0xffu;
#else
    return q8(v);
#endif
}
__device__ __forceinline__ unsigned enc4(float a, float b, float c, float d) {
#if HW_FP8
    int r = __builtin_amdgcn_cvt_pk_fp8_f32(a, b, 0, false);
    r = __builtin_amdgcn_cvt_pk_fp8_f32(c, d, r, true);
    return (unsigned)r;
#else
    return q8(a) | (q8(b) << 8) | (q8(c) << 16) | (q8(d) << 24);
#endif
}

// ---- degree histogram into 8 XCD-local copies; returns rank within copy ----
// (R11: restored R8 form — rank atomic lives here, overlapped with the
// histogram stream; k_fill consumes pos with NO atomic round trip.)
// Block 0 additionally zeroes psum/pcnt + X/Y sentinel rows.
__global__ void k_deg(const int* __restrict__ col, int* __restrict__ degc,
                      int* __restrict__ pos, float* __restrict__ psum,
                      unsigned char* __restrict__ X, unsigned char* __restrict__ Y,
                      int E) {
    if (blockIdx.x == 0) {
        for (int i = threadIdx.x; i < NUM_GRAPHS * 256 + NUM_GRAPHS; i += 256)
            psum[i] = 0.0f;
        if (threadIdx.x < 64) X[(size_t)N_NODES * 64 + threadIdx.x] = 0;
        if (threadIdx.x < 128) Y[(size_t)N_NODES * 128 + threadIdx.x] = 0;
    }
    int e = blockIdx.x * blockDim.x + threadIdx.x;
    if (e >= E) return;
    int c8 = (e >> 8) & 7;
    pos[e] = atomicAdd(&degc[c8 * N_NODES + col[e]], 1);
}

// ---- scan phase 1: per-block exclusive scan of PADDED degree + batch hist --
__global__ __launch_bounds__(256) void k_scan1(const int* __restrict__ degc,
                                               int* __restrict__ rowptr,
                                               int* __restrict__ bsum,
                                               const int* __restrict__ batch,
                                               float* __restrict__ pcnt, int N) {
    __shared__ int buf[256];
    __shared__ int hist[NUM_GRAPHS];
    int t = threadIdx.x;
    if (t < NUM_GRAPHS) hist[t] = 0;
    __syncthreads();  // hist must be zeroed before any wave's atomicAdd
    int i = blockIdx.x * 256 + t;
    int v = 0;
    if (i < N) {
        int tot = 0;
#pragma unroll
        for (int c = 0; c < 8; ++c) tot += degc[c * N_NODES + i];
        v = (tot + 7) & ~7;  // padded degree
        atomicAdd(&hist[batch[i]], 1);
    }
    buf[t] = v;
    __syncthreads();
#pragma unroll
    for (int off = 1; off < 256; off <<= 1) {
        int tmp = (t >= off) ? buf[t - off] : 0;
        __syncthreads();
        if (t >= off) buf[t] += tmp;
        __syncthreads();
    }
    if (i < N) rowptr[i] = buf[t] - v;  // exclusive within block
    if (t == 255) bsum[blockIdx.x] = buf[255];
    if (t < NUM_GRAPHS && hist[t] > 0) atomicAdd(&pcnt[t], (float)hist[t]);
}

// ---- scan phase 2 (folded): block-offset + per-copy slot bases + dinv +
//      xs (float4 rows) + Wt casts + sentinel-fill + rowptr[N] ---------------
__global__ __launch_bounds__(256) void k_scan3(int* __restrict__ rowptr,
                                               const int* __restrict__ bsum,
                                               const int* __restrict__ degc,
                                               int* __restrict__ base,
                                               float* __restrict__ dinv,
                                               const float* __restrict__ x,
                                               float* __restrict__ xs,
                                               unsigned short* __restrict__ csr,
                                               const float* __restrict__ W2,
                                               const float* __restrict__ W3,
                                               unsigned short* __restrict__ Wt2,
                                               unsigned short* __restrict__ Wt3,
                                               int N) {
    __shared__ int red[256];
    int t = threadIdx.x;
    int b = blockIdx.x;
    red[t] = (t < b) ? bsum[t] : 0;  // b <= 195 < 256
    __syncthreads();
#pragma unroll
    for (int off = 128; off > 0; off >>= 1) {
        if (t < off) red[t] += red[t + off];
        __syncthreads();
    }
    int boff = red[0];
    int i = b * 256 + t;
    if (i < N) {
        int rp = rowptr[i] + boff;
        rowptr[i] = rp;
        int run = rp, tot = 0;
#pragma unroll
        for (int c = 0; c < 8; ++c) {
            int d = degc[c * N_NODES + i];
            base[c * N_NODES + i] = run;
            run += d;
            tot += d;
        }
        int pdeg = (tot + 7) & ~7;
        // sentinel-fill pad slots -> point at the all-zero row N_NODES
        for (int j = rp + tot; j < rp + pdeg; ++j) csr[j] = (unsigned short)N_NODES;
        if (i == N - 1) rowptr[N] = rp + pdeg;  // padded total
        float dv = rsqrtf((float)tot + 1.0f);   // +1 = self loop
        dinv[i] = dv;
        f32x4 xv = {dv * x[i * 3 + 0], dv * x[i * 3 + 1], dv * x[i * 3 + 2], 0.0f};
        *(f32x4*)(xs + 4 * i) = xv;
    }
    if (i == 0) {  // zero sentinel row of xs
        f32x4 z = {0.0f, 0.0f, 0.0f, 0.0f};
        *(f32x4*)(xs + 4 * N) = z;
    }
    // folded weight cast+transpose (with /64 scale compensation)
    if (i < 64 * 128) {                       // Wt2: [f=128][k=64]
        int f = i / 64, k = i % 64;
        Wt2[i] = bf16_rne(W2[k * 128 + f] * 0.015625f);
    } else if (i < 64 * 128 + 128 * 256) {    // Wt3: [f=256][k=128]
        int j = i - 64 * 128;
        int f = j / 128, k = j % 128;
        Wt3[j] = bf16_rne(W3[k * 256 + f] * 0.015625f);
    }
}

// ---- CSR fill: no atomic; slot = base[copy][dst] + rank-within-copy --------
__global__ void k_fill(const int* __restrict__ row, const int* __restrict__ col,
                       const int* __restrict__ base, const int* __restrict__ pos,
                       unsigned short* __restrict__ csr, int E) {
    int e = blockIdx.x * blockDim.x + threadIdx.x;
    if (e >= E) return;
    int c8 = (e >> 8) & 7;
    csr[base[c8 * N_NODES + col[e]] + pos[e]] = (unsigned short)row[e];
}

// ---- fused layer 1: p1 = dv*(xs[v]+Σxs[r]); X = enc(64*dv*relu(p1 W1+b1)) --
// xs rows are float4 (one aligned dwordx4 request per edge).
__global__ void k_layer1(const float* __restrict__ xs, const float* __restrict__ dinv,
                         const int* __restrict__ rowptr,
                         const unsigned short* __restrict__ csr_src,
                         const float* __restrict__ W1, const float* __restrict__ b1,
                         unsigned char* __restrict__ out, int N) {
    int v = blockIdx.x * blockDim.x + threadIdx.x;
    if (v >= N) return;
    const unsigned* csr32 = (const unsigned*)csr_src;
    f32x4 a = *(const f32x4*)(xs + 4 * v);
    int j = rowptr[v];
    int j1 = rowptr[v + 1];
    for (; j + 4 <= j1; j += 4) {  // j stays multiple of 4 (rowptr mult of 8)
        unsigned p0 = csr32[(j >> 1) + 0];
        unsigned p1 = csr32[(j >> 1) + 1];
        int r0 = p0 & 0xFFFFu, r1 = p0 >> 16;
        int r2 = p1 & 0xFFFFu, r3 = p1 >> 16;
        f32x4 x0 = *(const f32x4*)(xs + 4 * r0);
        f32x4 x1 = *(const f32x4*)(xs + 4 * r1);
        f32x4 x2 = *(const f32x4*)(xs + 4 * r2);
        f32x4 x3 = *(const f32x4*)(xs + 4 * r3);
        a[0] += x0[0]; a[1] += x0[1]; a[2] += x0[2];
        a[0] += x1[0]; a[1] += x1[1]; a[2] += x1[2];
        a[0] += x2[0]; a[1] += x2[1]; a[2] += x2[2];
        a[0] += x3[0]; a[1] += x3[1]; a[2] += x3[2];
    }
    for (; j < j1; ++j) {  // dead with padded degrees
        int r = csr_src[j];
        f32x4 xv = *(const f32x4*)(xs + 4 * r);
        a[0] += xv[0]; a[1] += xv[1]; a[2] += xv[2];
    }
    float dv = dinv[v];
    float p0 = dv * a[0], p1 = dv * a[1], p2 = dv * a[2];
    float dv64 = dv * 64.0f;  // pre-scale for next prop + x64 codec shift
    unsigned char* ov = out + (long)v * 64;
#pragma unroll
    for (int f = 0; f < 64; f += 4) {
        float s[4];
#pragma unroll
        for (int t = 0; t < 4; ++t) {
            float sv = fmaf(p0, W1[f + t],
                       fmaf(p1, W1[64 + f + t],
                       fmaf(p2, W1[128 + f + t], b1[f + t])));
            s[t] = fmaxf(sv, 0.0f) * dv64;
        }
        *(unsigned*)(ov + f) = enc4(s[0], s[1], s[2], s[3]);
    }
}

// ---- FUSED prop + MFMA GEMM per 16-row m-tile; optional fused mean-pool ----
// R7 structure (4-row simultaneous gather); csr is ushort, index pairs loaded
// as uints (j stays a multiple of 8 -> uint-aligned).
template <int K, int F, bool PRESCALE, bool POOL>
__global__ __launch_bounds__(256, 4) void k_fused(
        const unsigned char* __restrict__ h, const float* __restrict__ dinv,
        const int* __restrict__ rowptr, const unsigned short* __restrict__ csr_src,
        const unsigned short* __restrict__ Wt, const float* __restrict__ b,
        unsigned char* __restrict__ out, const int* __restrict__ batch,
        float* __restrict__ psum, int N) {
    constexpr int NF = F / 16;    // f-tiles: 8 (F=128) / 16 (F=256)
    constexpr int FPW = NF / 4;   // f-tiles per wave: 2 / 4
    constexpr int KB = K / 32;    // k-blocks: 2 / 4
    constexpr int KL = K / 64;    // features (bytes) per lane in prop: 1 / 2
    constexpr int PADK = K + 8;
    __shared__ unsigned short plds[16][PADK];
    const unsigned* csr32 = (const unsigned*)csr_src;
    int wave = threadIdx.x >> 6;
    int lane = threadIdx.x & 63;
    int m0 = blockIdx.x * 16;

    // ---- phase 1: 4 rows per wave, simultaneous 8-wide gather batches ----
    int vr = m0 + wave * 4;
    float acc[4][KL];
    int j[4], j1[4];
#pragma unroll
    for (int r = 0; r < 4; ++r) {
        const unsigned char* hv = h + (long)(vr + r) * K + lane * KL;
        if (KL == 2) {
            unsigned u = *(const unsigned short*)hv;
            dq2(u, acc[r][0], acc[r][1]);
        } else {
            acc[r][0] = dq1(hv[0]);
        }
        j[r]  = __builtin_amdgcn_readfirstlane(rowptr[vr + r]);
        j1[r] = __builtin_amdgcn_readfirstlane(rowptr[vr + r + 1]);
    }
    while ((j[0] < j1[0]) || (j[1] < j1[1]) || (j[2] < j1[2]) || (j[3] < j1[3])) {
        bool act[4];
        int idx[4][8];
        unsigned tv[4][8];
        // phase a: index loads (uniform address, packed ushort pairs)
#pragma unroll
        for (int r = 0; r < 4; ++r) {
            act[r] = j[r] < j1[r];
            if (act[r]) {
#pragma unroll
                for (int u = 0; u < 4; ++u) {
                    unsigned pk = csr32[(j[r] >> 1) + u];
                    idx[r][2 * u]     = pk & 0xFFFFu;
                    idx[r][2 * u + 1] = pk >> 16;
                }
            }
        }
        // phase b: issue all gathers (up to 32 in flight)
#pragma unroll
        for (int r = 0; r < 4; ++r) {
            if (act[r]) {
                if (KL == 2) {
#pragma unroll
                    for (int u = 0; u < 8; ++u)
                        tv[r][u] = *(const unsigned short*)(h + (long)idx[r][u] * K + lane * 2);
                } else {
#pragma unroll
                    for (int u = 0; u < 8; ++u)
                        tv[r][u] = h[(long)idx[r][u] * K + lane];
                }
            }
        }
        // phase c: accumulate
#pragma unroll
        for (int r = 0; r < 4; ++r) {
            if (act[r]) {
                if (KL == 2) {
#pragma unroll
                    for (int u = 0; u < 8; ++u) {
                        float lo, hi;
                        dq2(tv[r][u], lo, hi);
                        acc[r][0] += lo;
                        acc[r][1] += hi;
                    }
                } else {
#pragma unroll
                    for (int u = 0; u < 8; ++u) acc[r][0] += dq1(tv[r][u]);
                }
                j[r] += 8;
            }
        }
    }
#pragma unroll
    for (int r = 0; r < 4; ++r) {
        float dv = dinv[vr + r];
        int rla = wave * 4 + r;
        if (KL == 2) {
            unsigned p = (unsigned)bf16_rne(dv * acc[r][0]) |
                         ((unsigned)bf16_rne(dv * acc[r][1]) << 16);
            *(unsigned*)&plds[rla][lane * 2] = p;
        } else {
            plds[rla][lane] = bf16_rne(dv * acc[r][0]);
        }
    }
    __syncthreads();

    // ---- phase 2: MFMA (layout verified R9/R11) ----
    int quad = lane >> 4;
    int l16 = lane & 15;
    bf16x8 afr[KB];
#pragma unroll
    for (int kb = 0; kb < KB; ++kb)
        afr[kb] = *(const bf16x8*)(const void*)&plds[l16][kb * 32 + quad * 8];
#pragma unroll
    for (int fi = 0; fi < FPW; ++fi) {
        int f0 = (wave * FPW + fi) * 16;
        const unsigned short* wrow = Wt + (long)(f0 + l16) * K + quad * 8;
        f32x4 acc4 = {0.f, 0.f, 0.f, 0.f};
#pragma unroll
        for (int kb = 0; kb < KB; ++kb) {
            bf16x8 bb = *(const bf16x8*)(const void*)(wrow + kb * 32);
            acc4 = __builtin_amdgcn_mfma_f32_16x16x32_bf16(afr[kb], bb, acc4, 0, 0, 0);
        }
        float bias = b[f0 + l16];
        if (POOL) {
            int g0 = batch[m0];
            int g15 = batch[m0 + 15];
            if (g0 == g15) {  // uniform block (all but ~15 of 3125)
                float s = fmaxf(acc4[0] + bias, 0.0f);
                s += fmaxf(acc4[1] + bias, 0.0f);
                s += fmaxf(acc4[2] + bias, 0.0f);
                s += fmaxf(acc4[3] + bias, 0.0f);
                s += __shfl_xor(s, 16);
                s += __shfl_xor(s, 32);
                if (quad == 0) atomicAdd(&psum[g0 * 256 + f0 + l16], s);
            } else {  // graph boundary inside block: per-element atomics
#pragma unroll
                for (int r = 0; r < 4; ++r) {
                    int m = m0 + quad * 4 + r;
                    float val = fmaxf(acc4[r] + bias, 0.0f);
                    atomicAdd(&psum[batch[m] * 256 + f0 + l16], val);
                }
            }
        } else {
#pragma unroll
            for (int r = 0; r < 4; ++r) {
                int m = m0 + quad * 4 + r;
                float val = fmaxf(acc4[r] + bias, 0.0f);
                if (PRESCALE) val *= dinv[m] * 64.0f;  // prop pre-scale + codec shift
                out[(long)m * F + f0 + l16] = (unsigned char)enc1(val);
            }
        }
    }
}

// ---- final FC --------------------------------------------------------------
__global__ void k_fc(const float* __restrict__ psum, const float* __restrict__ pcnt,
                     const float* __restrict__ Wfc, const float* __restrict__ bfc,
                     float* __restrict__ out) {
    int tid = blockIdx.x * blockDim.x + threadIdx.x;
    if (tid >= NUM_GRAPHS * NUM_CLASSES) return;
    int g = tid / NUM_CLASSES;
    int c = tid % NUM_CLASSES;
    float s = 0.0f;
#pragma unroll 8
    for (int k = 0; k < 256; ++k) s = fmaf(psum[g * 256 + k], Wfc[k * NUM_CLASSES + c], s);
    float cnt = pcnt[g];
    cnt = cnt > 1.0f ? cnt : 1.0f;
    out[tid] = s / cnt + bfc[c];
}

extern "C" void kernel_launch(void* const* d_in, const int* in_sizes, int n_in,
                              void* d_out, int out_size, void* d_ws, size_t ws_size,
                              hipStream_t stream) {
    const float* x     = (const float*)d_in[0];
    const int*   ei    = (const int*)d_in[1];
    const int*   batch = (const int*)d_in[2];
    const float* W1    = (const float*)d_in[3];
    const float* b1    = (const float*)d_in[4];
    const float* W2    = (const float*)d_in[5];
    const float* b2    = (const float*)d_in[6];
    const float* W3    = (const float*)d_in[7];
    const float* b3    = (const float*)d_in[8];
    const float* Wfc   = (const float*)d_in[9];
    const float* bfc   = (const float*)d_in[10];
    float* out = (float*)d_out;

    const int* row = ei;            // src
    const int* col = ei + N_EDGES;  // dst

    // ---- workspace layout (R11): R9 layout + pos restored. Byte offsets:
    //   xs     @ 0         ((N+1)*16 B = 800016 -> pad 800128)
    //   dinv   @ 800128    (200000 B)
    //   psum   @ 1000128   (16384 B)
    //   pcnt   @ 1016512   (64 B)
    //   X      @ 1016576   (128-aligned; (N+1)*64 = 3200064 -> pad 3200128)
    //   Y      @ 4216704   (128-aligned; (N+1)*128 = 6400128)
    //   Wt2    @ 10616832  (16384 B)
    //   Wt3    @ 10633216  (65536 B)
    //   degc   @ 10698752  (1600000 B)
    //   base   @ 12298752  (1600000 B)
    //   rowptr @ 13898752  (200004 -> pad 200064)
    //   csr16  @ 14098816  (CSR_CAP*2 = 2300000 B)
    //   pos    @ 16398816  (E*4 = 3200000 B)
    //   bsum   @ 19598816  (784 B)
    unsigned char* ws = (unsigned char*)d_ws;
    float*  xs   = (float*)ws;
    float*  dinv = (float*)(ws + 800128);
    float*  psum = (float*)(ws + 1000128);
    float*  pcnt = (float*)(ws + 1016512);
    unsigned char* X = ws + 1016576;
    unsigned char* Y = ws + 4216704;
    unsigned short* Wt2 = (unsigned short*)(ws + 10616832);
    unsigned short* Wt3 = (unsigned short*)(ws + 10633216);
    int* degc    = (int*)(ws + 10698752);
    int* base    = (int*)(ws + 12298752);
    int* rowptr  = (int*)(ws + 13898752);
    unsigned short* csr16 = (unsigned short*)(ws + 14098816);
    int* pos     = (int*)(ws + 16398816);
    int* bsum    = (int*)(ws + 19598816);

    // single memset: degc must be zero before k_deg's atomics
    hipMemsetAsync(degc, 0, 8 * N_NODES * sizeof(int), stream);

    // ---- CSR build + norms + pre-scaled x + weight casts ----
    // (k_deg block 0 also zeroes psum/pcnt and the X/Y sentinel rows)
    k_deg<<<nblk(N_EDGES), 256, 0, stream>>>(col, degc, pos, psum, X, Y, N_EDGES);
    k_scan1<<<SCAN_BLOCKS, 256, 0, stream>>>(degc, rowptr, bsum, batch, pcnt, N_NODES);
    k_scan3<<<SCAN_BLOCKS, 256, 0, stream>>>(rowptr, bsum, degc, base, dinv, x, xs,
                                             csr16, W2, W3, Wt2, Wt3, N_NODES);
    k_fill<<<nblk(N_EDGES), 256, 0, stream>>>(row, col, base, pos, csr16, N_EDGES);

    // ---- layer 1 (fused prop+linear): X = enc(64*d*relu((A~x)W1+b1)) -------
    k_layer1<<<nblk(N_NODES), 256, 0, stream>>>(xs, dinv, rowptr, csr16, W1, b1, X, N_NODES);

    int mtiles = N_NODES / 16;  // 3125, exact

    // ---- layer 2 fused: Y = enc(64*d*relu((A~-apply X) W2 + b2)) -----------
    k_fused<64, 128, true, false><<<mtiles, 256, 0, stream>>>(
        X, dinv, rowptr, csr16, Wt2, b2, Y, batch, psum, N_NODES);

    // ---- layer 3 fused + POOL: psum += relu((A~-apply Y) W3 + b3) ----------
    k_fused<128, 256, false, true><<<mtiles, 256, 0, stream>>>(
        Y, dinv, rowptr, csr16, Wt3, b3, (unsigned char*)nullptr, batch, psum, N_NODES);

    // ---- FC ----
    k_fc<<<nblk(NUM_GRAPHS * NUM_CLASSES), 256, 0, stream>>>(psum, pcnt, Wfc, bfc, out);
}